// Round 13
// baseline (144.864 us; speedup 1.0000x reference)
//
#include <hip/hip_runtime.h>

// ---------------------------------------------------------------------------
// 3-dispatch gather splat, COLUMN RECORDS split geo/ex, SGPR-walked splat.
// History: R7 fat records; R9 LDS staging; R10 atomic padding (NULL);
// R11 column records; R12 stored f32 x-table (123.3); R13 z-chunk ring
// (REVERTED: broke half-line write pairing); R14/15 depth-3 LDS pipeline
// (NULL); R16 no-LDS readlane splat (50.5us, VALUBusy 65% -> VALU-bound:
// 12 readlane + libm exp2f wrapper ~ 106cy/rec).
// R17 (compile-fail): "s"(m) constraint broke — compiler kept geo in VGPRs.
// R18/R19/R20: (1) readfirstlane on c0/c1/c2 -> the gidx chain is provably
// uniform (geo loads can scalarize); (2) readfirstlane on g.w -> meta/mask/
// z-test guaranteed SGPR/SALU, "s"(m) always valid; (3) ex[32B] lane-
// distributed (R16-proven), 8 readlanes per PASSING record only; (4) raw
// v_exp_f32 (normal-range inputs -> bit-identical to exp2f).
// (R20 = R18 resubmitted: rounds 11+12 benches were infra failures —
// "container failed twice", same signature as rounds 0/7 which passed on
// verbatim resubmit. Source audited for fault modes: none found.)
// Wave->tile t=bid*4+wid unchanged (write-coalescing, R13 lesson).
// ws use: counts 128KB | geo ~16MB | ex ~32MB.
// ---------------------------------------------------------------------------

#define NTILE 32768           // 32^3 tiles of 8^3 voxels
#define CAP   32              // records per center-slot: avg ~7.7
#define LOG2E 1.4426950408889634f

typedef unsigned long long ull;

__device__ __forceinline__ float fast_exp2(float x) {
    float r;
    asm("v_exp_f32 %0, %1" : "=v"(r) : "v"(x));
    return r;
}

// ---- kernel 1: per-(Gaussian, tx, ty) column record ------------------------
__global__ __launch_bounds__(256) void bin_prep_kernel(
    const float* __restrict__ centers,
    const float* __restrict__ sigmas,
    const float* __restrict__ intens,
    int*  __restrict__ counts,
    int4* __restrict__ geoL,
    int4* __restrict__ exL,
    int N)
{
    int g = blockIdx.x * 256 + threadIdx.x;
    if (g >= N) return;
    int txi = blockIdx.y % 3;          // wave-uniform
    int tyi = blockIdx.y / 3;

    float cx = centers[3*g+0] * 255.0f;
    float cy = centers[3*g+1] * 255.0f;
    float cz = centers[3*g+2] * 255.0f;
    float sig = sigmas[g];
    float cut = 3.0f * sig * 255.0f;
    float cc[3] = {cx, cy, cz};
    int mn[3], mx[3];
    #pragma unroll
    for (int a = 0; a < 3; ++a) {
        mn[a] = (int)floorf(fmaxf(cc[a] - cut, 0.0f));
        mx[a] = (int)fminf(floorf(fminf(cc[a] + cut, 255.0f)) + 1.0f, 256.0f); // exclusive
    }
    float s255 = sig * 255.0f;
    float w2 = -0.5f * LOG2E / (s255 * s255);
    float inten = intens[g];

    int t0x = mn[0] >> 3, t1x = (mx[0] - 1) >> 3;
    int t0y = mn[1] >> 3, t1y = (mx[1] - 1) >> 3;

    int tx = t0x + txi; if (tx > t1x) return;
    int ty = t0y + tyi; if (ty > t1y) return;

    int ox = tx << 3, oy = ty << 3;
    int lox = max(mn[0] - ox, 0), hix = min(mx[0] - ox, 8);
    int loy = max(mn[1] - oy, 0), hiy = min(mx[1] - oy, 8);

    // clipped, intensity-folded x-table (v_exp_f32 == exp2f on normal inputs)
    float ex[8];
    #pragma unroll
    for (int i = 0; i < 8; ++i) {
        float d = (float)(ox + i) - cx;
        float v = fast_exp2(d * d * w2) * inten;
        ex[i] = (i >= lox && i < hix) ? v : 0.0f;
    }

    int tzc = ((int)cz) >> 3;                  // cz in [0,255) -> tzc in [0,31]
    int t = (tx << 10) | (ty << 5) | tzc;
    unsigned meta = (unsigned)mn[2] | ((unsigned)(mx[2] - 1) << 8)
                  | ((unsigned)loy << 16) | ((unsigned)hiy << 19);

    int slot = atomicAdd(&counts[t], 1);
    if (slot < CAP) {
        int gi = t * CAP + slot;
        geoL[gi] = make_int4(__float_as_int(cy), __float_as_int(cz),
                             __float_as_int(w2), (int)meta);
        exL[2*gi]   = make_int4(__float_as_int(ex[0]), __float_as_int(ex[1]),
                                __float_as_int(ex[2]), __float_as_int(ex[3]));
        exL[2*gi+1] = make_int4(__float_as_int(ex[4]), __float_as_int(ex[5]),
                                __float_as_int(ex[6]), __float_as_int(ex[7]));
    }
}

// ---- kernel 2: gather — one wave/tile, uniform geo walk + lane-held ex -----
__global__ __launch_bounds__(256) void splat_main(
    const int*  __restrict__ counts,
    const int4* __restrict__ geoL,
    const int4* __restrict__ exL,
    float* __restrict__ vol)
{
    int wid = threadIdx.x >> 6;
    int lane = threadIdx.x & 63;
    int t = __builtin_amdgcn_readfirstlane(blockIdx.x * 4 + wid);
    int ox = (t >> 10) << 3, oy = ((t >> 5) & 31) << 3, oz = (t & 31) << 3;
    int tz = t & 31;
    int ly = lane >> 3, lz = lane & 7;

    // readfirstlane: mark counts uniform so the gidx chain (and ideally the
    // geo loads) scalarize — this is what R17's compile needed.
    int c0 = (tz > 0)  ? __builtin_amdgcn_readfirstlane(counts[t - 1]) : 0;
    if (c0 > CAP) c0 = CAP;
    int c1 = __builtin_amdgcn_readfirstlane(counts[t]);
    if (c1 > CAP) c1 = CAP;
    int c2 = (tz < 31) ? __builtin_amdgcn_readfirstlane(counts[t + 1]) : 0;
    if (c2 > CAP) c2 = CAP;
    int e1 = c0 + c1, ntot = e1 + c2;

    int gbase = (t - 1) * CAP;
    // branch-free uniform record index: step over the unused slot tails.
    auto gidx = [&](int r) -> int {
        int a = (r >= c0) ? (CAP - c0) : 0;   // s_cselect
        int b = (r >= e1) ? (CAP - c1) : 0;
        return gbase + r + a + b;             // pure SALU
    };

    // lane-side ex: lane k holds record k's 8-tap table (phase p: record k+64p)
    int4 EX0, EX1;
    auto load_ex = [&](int r) {
        int gi = (r < ntot) ? gidx(r) : (t * CAP);   // safe dummy
        EX0 = exL[2*gi]; EX1 = exL[2*gi+1];
    };
    load_ex(lane);

    float fy = (float)(oy + ly);
    float fz = (float)(oz + lz);

    float acc[8];
    #pragma unroll
    for (int i = 0; i < 8; ++i) acc[i] = 0.0f;

    // kk = readlane index (record within current 64-phase); g = geo record
    auto body = [&](int kk, int4 g) {
        // guarantee SGPR meta (and thus SALU mask build + valid "s"(m))
        unsigned meta = (unsigned)__builtin_amdgcn_readfirstlane(g.w);
        int mnz  = (int)(meta & 0xFF);
        int mxzi = (int)((meta >> 8) & 0xFF);
        int loz = mnz - oz;      if (loz < 0) loz = 0;
        int hiz = mxzi + 1 - oz; if (hiz > 8) hiz = 8;
        if (loz < hiz) {                       // wave-uniform scalar branch
            int loy_ = (int)((meta >> 16) & 7);
            int hiy_ = (int)((meta >> 19) & 0xF);   // in [1,8]
            ull ym = ((~0ull) << (loy_ << 3)) & ((~0ull) >> (64 - (hiy_ << 3)));
            unsigned zpat = (0xFFu >> (8 - hiz)) & (0xFFu << loz);
            unsigned zrep = zpat * 0x01010101u;
            ull m = (((ull)zrep << 32) | (ull)zrep) & ym;

            float cyv = __int_as_float(g.x);
            float czv = __int_as_float(g.y);
            float w2v = __int_as_float(g.z);

            float dy = fy - cyv, dz = fz - czv;
            float e = fast_exp2(fmaf(dy, dy, dz * dz) * w2v);
            float em;
            asm("v_cndmask_b32 %0, 0, %1, %2" : "=v"(em) : "v"(e), "s"(m));

            float ex0 = __int_as_float(__builtin_amdgcn_readlane(EX0.x, kk));
            float ex1 = __int_as_float(__builtin_amdgcn_readlane(EX0.y, kk));
            float ex2 = __int_as_float(__builtin_amdgcn_readlane(EX0.z, kk));
            float ex3 = __int_as_float(__builtin_amdgcn_readlane(EX0.w, kk));
            float ex4 = __int_as_float(__builtin_amdgcn_readlane(EX1.x, kk));
            float ex5 = __int_as_float(__builtin_amdgcn_readlane(EX1.y, kk));
            float ex6 = __int_as_float(__builtin_amdgcn_readlane(EX1.z, kk));
            float ex7 = __int_as_float(__builtin_amdgcn_readlane(EX1.w, kk));

            acc[0] = fmaf(ex0, em, acc[0]);
            acc[1] = fmaf(ex1, em, acc[1]);
            acc[2] = fmaf(ex2, em, acc[2]);
            acc[3] = fmaf(ex3, em, acc[3]);
            acc[4] = fmaf(ex4, em, acc[4]);
            acc[5] = fmaf(ex5, em, acc[5]);
            acc[6] = fmaf(ex6, em, acc[6]);
            acc[7] = fmaf(ex7, em, acc[7]);
        }
    };

    // depth-6 rotation over the geo stream (uniform addresses).
    // geoL/exL are tail-padded so gidx(k+6) overreads stay in-bounds.
    int4 g0 = geoL[gidx(0)], g1 = geoL[gidx(1)], g2 = geoL[gidx(2)];
    int4 g3 = geoL[gidx(3)], g4 = geoL[gidx(4)], g5 = geoL[gidx(5)];
    int n1 = ntot < 64 ? ntot : 64;
    int k = 0;
    for (; k < n1; ++k) {
        int4 gn = geoL[gidx(k + 6)];
        body(k, g0);
        g0 = g1; g1 = g2; g2 = g3; g3 = g4; g4 = g5; g5 = gn;
    }
    if (ntot > 64) {                       // Poisson tail, rare
        load_ex(lane + 64);
        for (; k < ntot; ++k) {
            int4 gn = geoL[gidx(k + 6)];
            body(k - 64, g0);
            g0 = g1; g1 = g2; g2 = g3; g3 = g4; g4 = g5; g5 = gn;
        }
    }

    int ybase = ((oy + ly) << 8) + (oz + lz);
    #pragma unroll
    for (int i = 0; i < 8; ++i)
        vol[((ox + i) << 16) + ybase] = acc[i];
}

// ---------------------------------------------------------------------------
extern "C" void kernel_launch(void* const* d_in, const int* in_sizes, int n_in,
                              void* d_out, int out_size, void* d_ws, size_t ws_size,
                              hipStream_t stream) {
    const float* centers = (const float*)d_in[0];   // (N,3)
    const float* sigmas  = (const float*)d_in[1];   // (N,)
    const float* intens  = (const float*)d_in[2];   // (N,)
    float* vol = (float*)d_out;                     // 256^3 fp32
    const int N = in_sizes[1];

    // ws: counts 128KB | geo (NTILE*CAP+128)*16B | ex (NTILE*CAP+128)*32B
    char* ws = (char*)d_ws;
    int*  counts = (int*)ws;
    int4* geoL   = (int4*)(ws + (size_t)NTILE * sizeof(int));
    int4* exL    = (int4*)(ws + (size_t)NTILE * sizeof(int)
                              + ((size_t)NTILE * CAP + 128) * 16);

    (void)hipMemsetAsync(counts, 0, (size_t)NTILE * sizeof(int), stream);

    int gblocks = (N + 255) / 256;
    bin_prep_kernel<<<dim3(gblocks, 9), 256, 0, stream>>>(centers, sigmas, intens,
                                                          counts, geoL, exL, N);
    splat_main<<<NTILE / 4, 256, 0, stream>>>(counts, geoL, exL, vol);
}

// Round 15
// 132.673 us; speedup vs baseline: 1.0919x; 1.0919x over previous
//
#include <hip/hip_runtime.h>

// ---------------------------------------------------------------------------
// 3-dispatch gather splat, COLUMN RECORDS, ONE WAVE PER 4 Z-TILES.
// History: R12 LDS-staged 48B records (best: splat ~42-46, total 123.3);
// R13 z-chunk ring REVERTED (broke write pairing); R14 depth-3 NULL;
// R16 readlane (50.5, VALU-bound); R18 SALU-offload FAILED (hipcc won't
// scalarize pointer-chased loads); R21 compile-fail: tz0 used RAW wid
// (threadIdx-derived -> divergence analysis marked m divergent -> "s"(m)
// got a VGPR pair). R22 fix: wid = readfirstlane(threadIdx.x>>6) — per-wave
// first-lane value == wid, provably uniform (exactly what R12's
// t=readfirstlane(bid*4+wid) relied on). Rest byte-identical to R21.
// Model: calibrated DS-pipe wall (per-CU, ~6cy/op): R12 = 138 DS ops/wave x
// 6cy x 128 waves/CU = 44us == measured. Amortize: one wave owns 4
// consecutive z-tiles, scans slots tz0-1..tz0+4 ONCE; each record's ds_read
// serves up to 4 tiles -> 276 DS ops x 32 wave-units/CU = ~22us. Wave writes
// z=0..31 itself -> full 64B lines (R13 lesson). Record order per tile
// identical to R12 -> absmax unchanged. ws ~50.5 MB.
// ---------------------------------------------------------------------------

#define NTILE 32768           // 32^3 tiles of 8^3 voxels
#define CAP   32              // records per center-slot: avg ~7.7
#define LOG2E 1.4426950408889634f

typedef unsigned long long ull;

__device__ __forceinline__ float fast_exp2(float x) {
    float r;
    asm("v_exp_f32 %0, %1" : "=v"(r) : "v"(x));
    return r;
}

struct __align__(16) Rec {    // 48 B, one per (gaussian, x-y column)
    float cy, cz, w2;         // voxel-space center y,z; exp2 scale
    unsigned meta;            // [0:8) mnz, [8:16) mxz_incl, [16:19) loy, [19:23) hiy
    float ex[8];              // clipped, intensity-folded x-table (zeros outside)
};

// ---- kernel 1: per-(Gaussian, tx, ty) column record ------------------------
__global__ __launch_bounds__(256) void bin_prep_kernel(
    const float* __restrict__ centers,
    const float* __restrict__ sigmas,
    const float* __restrict__ intens,
    int*  __restrict__ counts,
    Rec*  __restrict__ list,
    int N)
{
    int g = blockIdx.x * 256 + threadIdx.x;
    if (g >= N) return;
    int txi = blockIdx.y % 3;          // wave-uniform
    int tyi = blockIdx.y / 3;

    float cx = centers[3*g+0] * 255.0f;
    float cy = centers[3*g+1] * 255.0f;
    float cz = centers[3*g+2] * 255.0f;
    float sig = sigmas[g];
    float cut = 3.0f * sig * 255.0f;
    float cc[3] = {cx, cy, cz};
    int mn[3], mx[3];
    #pragma unroll
    for (int a = 0; a < 3; ++a) {
        mn[a] = (int)floorf(fmaxf(cc[a] - cut, 0.0f));
        mx[a] = (int)fminf(floorf(fminf(cc[a] + cut, 255.0f)) + 1.0f, 256.0f); // exclusive
    }
    float s255 = sig * 255.0f;
    float w2 = -0.5f * LOG2E / (s255 * s255);
    float inten = intens[g];

    int t0x = mn[0] >> 3, t1x = (mx[0] - 1) >> 3;
    int t0y = mn[1] >> 3, t1y = (mx[1] - 1) >> 3;

    int tx = t0x + txi; if (tx > t1x) return;
    int ty = t0y + tyi; if (ty > t1y) return;

    int ox = tx << 3, oy = ty << 3;
    int lox = max(mn[0] - ox, 0), hix = min(mx[0] - ox, 8);
    int loy = max(mn[1] - oy, 0), hiy = min(mx[1] - oy, 8);

    // clipped, intensity-folded x-table (v_exp_f32 == exp2f on normal inputs)
    float ex[8];
    #pragma unroll
    for (int i = 0; i < 8; ++i) {
        float d = (float)(ox + i) - cx;
        float v = fast_exp2(d * d * w2) * inten;
        ex[i] = (i >= lox && i < hix) ? v : 0.0f;
    }

    int tzc = ((int)cz) >> 3;                  // cz in [0,255) -> tzc in [0,31]
    int t = (tx << 10) | (ty << 5) | tzc;
    unsigned meta = (unsigned)mn[2] | ((unsigned)(mx[2] - 1) << 8)
                  | ((unsigned)loy << 16) | ((unsigned)hiy << 19);

    int slot = atomicAdd(&counts[t], 1);
    if (slot < CAP) {
        int4* p = (int4*)&list[(size_t)t * CAP + slot];
        p[0] = make_int4(__float_as_int(cy), __float_as_int(cz),
                         __float_as_int(w2), (int)meta);
        p[1] = make_int4(__float_as_int(ex[0]), __float_as_int(ex[1]),
                         __float_as_int(ex[2]), __float_as_int(ex[3]));
        p[2] = make_int4(__float_as_int(ex[4]), __float_as_int(ex[5]),
                         __float_as_int(ex[6]), __float_as_int(ex[7]));
    }
}

// ---- kernel 2: gather — one wave per 4 z-tiles, 6-slot shared scan ---------
__global__ __launch_bounds__(256) void splat_main(
    const int*  __restrict__ counts,
    const Rec*  __restrict__ list,
    float* __restrict__ vol)
{
    // per-wave dense buffer: 6 slots x CAP records x 3 int4 + 3 pad = 579
    // -> 9264 B/wave, 37,056 B/block (4 blocks/CU, 16 waves/CU).
    __shared__ int4 sh[4][6 * CAP * 3 + 3];

    // readfirstlane -> wave-uniform wid (per-wave first-lane value == wid).
    // CRITICAL: raw threadIdx-derived wid poisons uniformity analysis and
    // the "s"(m) asm constraint below fails to compile (R21 lesson).
    int wid = __builtin_amdgcn_readfirstlane((int)(threadIdx.x >> 6));
    int lane = threadIdx.x & 63;
    int bid = __builtin_amdgcn_readfirstlane(blockIdx.x);
    int col = bid >> 1, h = bid & 1;
    int tx = col >> 5, ty = col & 31;
    int tz0 = (h << 4) | (wid << 2);       // wave's first z-tile (0,4,..,28)
    int ox = tx << 3, oy = ty << 3, oz0 = tz0 << 3;
    int ly = lane >> 3, lz = lane & 7;
    int colbase = (tx << 10) | (ty << 5);

    // slot counts + dense offsets (slots tz0-1 .. tz0+4)
    int cnt[6], off[6];
    int run = 0, ntot = 0;
    #pragma unroll
    for (int s = 0; s < 6; ++s) {
        int slot = tz0 - 1 + s;
        int c = (slot >= 0 && slot < 32) ? counts[colbase + slot] : 0;
        if (c > CAP) c = CAP;
        cnt[s] = c; off[s] = run; run += 3 * c; ntot += c;
    }

    // stage the 6 slot lists densely (coalesced int4 chunks, wave-private)
    #pragma unroll
    for (int s = 0; s < 6; ++s) {
        const int4* src = (const int4*)(list + (size_t)(colbase + tz0 - 1 + s) * CAP);
        int ch = 3 * cnt[s];
        for (int j = lane; j < ch; j += 64)
            sh[wid][off[s] + j] = src[j];
    }

    float fy  = (float)(oy + ly);
    float fz0 = (float)(oz0 + lz);

    float acc[4][8];
    #pragma unroll
    for (int j = 0; j < 4; ++j)
        #pragma unroll
        for (int i = 0; i < 8; ++i) acc[j][i] = 0.0f;

    const int4* P = sh[wid];

    // flat walk, depth-2 register rotation; each record serves up to 4 tiles
    int4 A0 = P[0], A1 = P[1], A2 = P[2];
    for (int k = 0; k < ntot; ++k) {
        int b = (k + 1) * 3;
        int4 B0 = P[b], B1 = P[b + 1], B2 = P[b + 2];

        unsigned meta = (unsigned)__builtin_amdgcn_readfirstlane(A0.w);
        int mnz  = (int)(meta & 0xFF);
        int mxzi = (int)((meta >> 8) & 0xFF);
        int loy_ = (int)((meta >> 16) & 7);
        int hiy_ = (int)((meta >> 19) & 0xF);   // in [1,8]
        ull ym = ((~0ull) << (loy_ << 3)) & ((~0ull) >> (64 - (hiy_ << 3)));

        float cyv = __int_as_float(A0.x), czv = __int_as_float(A0.y);
        float w2v = __int_as_float(A0.z);
        float dy = fy - cyv;
        float dy2 = dy * dy;

        #pragma unroll
        for (int j = 0; j < 4; ++j) {
            int ozj = oz0 + 8 * j;
            int lozj = mnz - ozj;      if (lozj < 0) lozj = 0;
            int hizj = mxzi + 1 - ozj; if (hizj > 8) hizj = 8;
            if (lozj < hizj) {                 // wave-uniform scalar branch
                unsigned zpat = (0xFFu >> (8 - hizj)) & (0xFFu << lozj);
                unsigned zrep = zpat * 0x01010101u;
                ull m = (((ull)zrep << 32) | (ull)zrep) & ym;

                float dz = (fz0 + (float)(8 * j)) - czv;
                float e = fast_exp2(fmaf(dz, dz, dy2) * w2v);
                float em;
                asm("v_cndmask_b32 %0, 0, %1, %2" : "=v"(em) : "v"(e), "s"(m));

                acc[j][0] = fmaf(__int_as_float(A1.x), em, acc[j][0]);
                acc[j][1] = fmaf(__int_as_float(A1.y), em, acc[j][1]);
                acc[j][2] = fmaf(__int_as_float(A1.z), em, acc[j][2]);
                acc[j][3] = fmaf(__int_as_float(A1.w), em, acc[j][3]);
                acc[j][4] = fmaf(__int_as_float(A2.x), em, acc[j][4]);
                acc[j][5] = fmaf(__int_as_float(A2.y), em, acc[j][5]);
                acc[j][6] = fmaf(__int_as_float(A2.z), em, acc[j][6]);
                acc[j][7] = fmaf(__int_as_float(A2.w), em, acc[j][7]);
            }
        }
        A0 = B0; A1 = B1; A2 = B2;
    }

    // epilogue: this wave writes z = oz0..oz0+31 itself -> full 64B lines
    int ybase = (oy + ly) << 8;
    #pragma unroll
    for (int j = 0; j < 4; ++j) {
        int zabs = oz0 + 8 * j + lz;
        #pragma unroll
        for (int i = 0; i < 8; ++i)
            vol[((ox + i) << 16) + ybase + zabs] = acc[j][i];
    }
}

// ---------------------------------------------------------------------------
extern "C" void kernel_launch(void* const* d_in, const int* in_sizes, int n_in,
                              void* d_out, int out_size, void* d_ws, size_t ws_size,
                              hipStream_t stream) {
    const float* centers = (const float*)d_in[0];   // (N,3)
    const float* sigmas  = (const float*)d_in[1];   // (N,)
    const float* intens  = (const float*)d_in[2];   // (N,)
    float* vol = (float*)d_out;                     // 256^3 fp32
    const int N = in_sizes[1];

    // workspace: counts 128KB | list NTILE*CAP*48B ~= 50.3 MiB
    char* ws = (char*)d_ws;
    int*  counts = (int*)ws;
    Rec*  list   = (Rec*)(ws + (size_t)NTILE * sizeof(int));

    (void)hipMemsetAsync(counts, 0, (size_t)NTILE * sizeof(int), stream);

    int gblocks = (N + 255) / 256;
    bin_prep_kernel<<<dim3(gblocks, 9), 256, 0, stream>>>(centers, sigmas, intens,
                                                          counts, list, N);
    // 2048 blocks: (tx,ty) x {lower,upper half}; 4 waves x 4 z-tiles each
    splat_main<<<2048, 256, 0, stream>>>(counts, list, vol);
}

// Round 16
// 122.323 us; speedup vs baseline: 1.1843x; 1.0846x over previous
//
#include <hip/hip_runtime.h>

// ---------------------------------------------------------------------------
// 3-dispatch gather splat, COLUMN RECORDS, one wave per 8^3 tile.
// SESSION BEST = this structure (round 5: 123.3us total). Six splat
// restructures since (depth-3 LDS, readlane, SALU-offload, 4-z-tile
// amortize) all landed 46-67us -> splat is latency-bound and invariant
// ~45us under issue-pressure redistribution; models for DS-throughput and
// VALU-throughput both falsified. This round: restore round-5 source
// EXACTLY and apply the single verified-safe delta — exp2f -> raw
// v_exp_f32 (fast_exp2). R9 measured ~106cy/rec VALU vs ~58 static (libm
// OCML denorm-guard overhead); R22 verified fast_exp2 passes with
// bit-identical absmax (0.0078125). bin_prep: 8 exp2/candidate (VALU bulk);
// splat: 1/rec + shorter serial chain for the depth-2 pipeline to cover.
// Wave->tile t=bid*4+wid is LOAD-BEARING (R13 lesson: sibling-wave 32B
// half-line write pairing; WRITE_SIZE must stay exactly 64MB).
// ws use ~50.5 MB.
// ---------------------------------------------------------------------------

#define NTILE 32768           // 32^3 tiles of 8^3 voxels
#define CAP   32              // records per center-slot: avg ~7.7, Poisson-safe
#define LOG2E 1.4426950408889634f

typedef unsigned long long ull;

__device__ __forceinline__ float fast_exp2(float x) {
    float r;
    asm("v_exp_f32 %0, %1" : "=v"(r) : "v"(x));
    return r;
}

struct __align__(16) Rec {    // 48 B, one per (gaussian, x-y column)
    float cy, cz, w2;         // voxel-space center y,z; exp2 scale
    unsigned meta;            // [0:8) mnz, [8:16) mxz_incl, [16:19) loy, [19:23) hiy
    float ex[8];              // clipped, intensity-folded x-table (zeros outside)
};

// ---- kernel 1: per-(Gaussian, tx, ty) column record ------------------------
__global__ __launch_bounds__(256) void bin_prep_kernel(
    const float* __restrict__ centers,
    const float* __restrict__ sigmas,
    const float* __restrict__ intens,
    int*  __restrict__ counts,
    Rec*  __restrict__ list,
    int N)
{
    int g = blockIdx.x * 256 + threadIdx.x;
    if (g >= N) return;
    int txi = blockIdx.y % 3;          // wave-uniform
    int tyi = blockIdx.y / 3;

    float cx = centers[3*g+0] * 255.0f;
    float cy = centers[3*g+1] * 255.0f;
    float cz = centers[3*g+2] * 255.0f;
    float sig = sigmas[g];
    float cut = 3.0f * sig * 255.0f;
    float cc[3] = {cx, cy, cz};
    int mn[3], mx[3];
    #pragma unroll
    for (int a = 0; a < 3; ++a) {
        mn[a] = (int)floorf(fmaxf(cc[a] - cut, 0.0f));
        mx[a] = (int)fminf(floorf(fminf(cc[a] + cut, 255.0f)) + 1.0f, 256.0f); // exclusive
    }
    float s255 = sig * 255.0f;
    float w2 = -0.5f * LOG2E / (s255 * s255);
    float inten = intens[g];

    int t0x = mn[0] >> 3, t1x = (mx[0] - 1) >> 3;
    int t0y = mn[1] >> 3, t1y = (mx[1] - 1) >> 3;

    int tx = t0x + txi; if (tx > t1x) return;
    int ty = t0y + tyi; if (ty > t1y) return;

    int ox = tx << 3, oy = ty << 3;
    int lox = max(mn[0] - ox, 0), hix = min(mx[0] - ox, 8);
    int loy = max(mn[1] - oy, 0), hiy = min(mx[1] - oy, 8);

    // clipped, intensity-folded x-table (v_exp_f32 == exp2f on these
    // normal-range inputs; verified bit-identical absmax in R22)
    float ex[8];
    #pragma unroll
    for (int i = 0; i < 8; ++i) {
        float d = (float)(ox + i) - cx;
        float v = fast_exp2(d * d * w2) * inten;
        ex[i] = (i >= lox && i < hix) ? v : 0.0f;
    }

    int tzc = ((int)cz) >> 3;                  // cz in [0,255) -> tzc in [0,31]
    int t = (tx << 10) | (ty << 5) | tzc;
    unsigned meta = (unsigned)mn[2] | ((unsigned)(mx[2] - 1) << 8)
                  | ((unsigned)loy << 16) | ((unsigned)hiy << 19);

    int slot = atomicAdd(&counts[t], 1);
    if (slot < CAP) {
        int4* p = (int4*)&list[(size_t)t * CAP + slot];
        p[0] = make_int4(__float_as_int(cy), __float_as_int(cz),
                         __float_as_int(w2), (int)meta);
        p[1] = make_int4(__float_as_int(ex[0]), __float_as_int(ex[1]),
                         __float_as_int(ex[2]), __float_as_int(ex[3]));
        p[2] = make_int4(__float_as_int(ex[4]), __float_as_int(ex[5]),
                         __float_as_int(ex[6]), __float_as_int(ex[7]));
    }
}

// ---- kernel 2: gather — one wave per tile, scans center-slots tz-1..tz+1 ---
__global__ __launch_bounds__(256) void splat_main(
    const int*  __restrict__ counts,
    const Rec*  __restrict__ list,
    float* __restrict__ vol)
{
    // concatenated staging: up to 3*CAP records (3 int4 each) + pad record
    __shared__ int4 sh[4][(3 * CAP + 2) * 3];   // 18.8 KB/block -> 8 blocks/CU

    int wid = threadIdx.x >> 6;
    int lane = threadIdx.x & 63;
    int t = __builtin_amdgcn_readfirstlane(blockIdx.x * 4 + wid);
    int ox = (t >> 10) << 3, oy = ((t >> 5) & 31) << 3, oz = (t & 31) << 3;
    int tz = t & 31;
    int ly = lane >> 3, lz = lane & 7;

    int c0 = (tz > 0)  ? counts[t - 1] : 0;  if (c0 > CAP) c0 = CAP;
    int c1 = counts[t];                       if (c1 > CAP) c1 = CAP;
    int c2 = (tz < 31) ? counts[t + 1] : 0;  if (c2 > CAP) c2 = CAP;
    int n01 = c0 + c1, ntot = n01 + c2;

    const int4* s0 = (const int4*)(list + (long)(t - 1) * CAP);  // unused if c0==0
    const int4* s1 = (const int4*)(list + (long)t * CAP);
    const int4* s2 = (const int4*)(list + (long)(t + 1) * CAP);

    // stage concatenated lists, coalesced int4 chunks, wave-private (no barrier)
    int e0 = 3 * c0, e1 = 3 * n01, etot = 3 * ntot;
    for (int k = lane; k < etot; k += 64) {
        const int4* src; int off;
        if (k < e0)      { src = s0; off = k; }
        else if (k < e1) { src = s1; off = k - e0; }
        else             { src = s2; off = k - e1; }
        sh[wid][k] = src[off];
    }

    float fy = (float)(oy + ly);
    float fz = (float)(oz + lz);

    float acc[8];
    #pragma unroll
    for (int i = 0; i < 8; ++i) acc[i] = 0.0f;

    const int4* P = sh[wid];

    // depth-2 register pipeline over LDS broadcast reads
    int4 a0 = P[0], a1 = P[1], a2 = P[2];
    for (int k = 0; k < ntot; ++k) {
        int b = (k + 1) * 3;
        int4 b0 = P[b], b1 = P[b + 1], b2 = P[b + 2];

        unsigned meta = (unsigned)__builtin_amdgcn_readfirstlane(a0.w);
        int mnz  = (int)(meta & 0xFF);
        int mxzi = (int)((meta >> 8) & 0xFF);
        int loz = mnz - oz;      if (loz < 0) loz = 0;
        int hiz = mxzi + 1 - oz; if (hiz > 8) hiz = 8;
        if (loz < hiz) {                       // z-overlap (wave-uniform branch)
            int loy_ = (int)((meta >> 16) & 7);
            int hiy_ = (int)((meta >> 19) & 0xF);   // in [1,8]
            ull ym = ((~0ull) << (loy_ << 3)) & ((~0ull) >> (64 - (hiy_ << 3)));
            unsigned zpat = (0xFFu >> (8 - hiz)) & (0xFFu << loz);
            unsigned zrep = zpat * 0x01010101u;
            ull m = (((ull)zrep << 32) | (ull)zrep) & ym;

            float cyv = __int_as_float(a0.x), czv = __int_as_float(a0.y);
            float w2v = __int_as_float(a0.z);

            float dy = fy - cyv, dz = fz - czv;
            float e = fast_exp2(fmaf(dy, dy, dz * dz) * w2v);
            float em;
            asm("v_cndmask_b32 %0, 0, %1, %2" : "=v"(em) : "v"(e), "s"(m));

            acc[0] = fmaf(__int_as_float(a1.x), em, acc[0]);
            acc[1] = fmaf(__int_as_float(a1.y), em, acc[1]);
            acc[2] = fmaf(__int_as_float(a1.z), em, acc[2]);
            acc[3] = fmaf(__int_as_float(a1.w), em, acc[3]);
            acc[4] = fmaf(__int_as_float(a2.x), em, acc[4]);
            acc[5] = fmaf(__int_as_float(a2.y), em, acc[5]);
            acc[6] = fmaf(__int_as_float(a2.z), em, acc[6]);
            acc[7] = fmaf(__int_as_float(a2.w), em, acc[7]);
        }
        a0 = b0; a1 = b1; a2 = b2;
    }

    int ybase = ((oy + ly) << 8) + (oz + lz);
    #pragma unroll
    for (int i = 0; i < 8; ++i)
        vol[((ox + i) << 16) + ybase] = acc[i];
}

// ---------------------------------------------------------------------------
extern "C" void kernel_launch(void* const* d_in, const int* in_sizes, int n_in,
                              void* d_out, int out_size, void* d_ws, size_t ws_size,
                              hipStream_t stream) {
    const float* centers = (const float*)d_in[0];   // (N,3)
    const float* sigmas  = (const float*)d_in[1];   // (N,)
    const float* intens  = (const float*)d_in[2];   // (N,)
    float* vol = (float*)d_out;                     // 256^3 fp32
    const int N = in_sizes[1];

    // workspace: counts 128KB | list NTILE*CAP*48B ~= 50.3 MiB
    char* ws = (char*)d_ws;
    int*  counts = (int*)ws;
    Rec*  list   = (Rec*)(ws + (size_t)NTILE * sizeof(int));

    (void)hipMemsetAsync(counts, 0, (size_t)NTILE * sizeof(int), stream);

    int gblocks = (N + 255) / 256;
    bin_prep_kernel<<<dim3(gblocks, 9), 256, 0, stream>>>(centers, sigmas, intens,
                                                          counts, list, N);
    splat_main<<<NTILE / 4, 256, 0, stream>>>(counts, list, vol);
}